// Round 1
// baseline (102.666 us; speedup 1.0000x reference)
//
#include <hip/hip_runtime.h>
#include <hip/hip_bf16.h>

#define B_ 32
#define N_ 1024
#define F_ 128
#define ALPHA_ 0.2f

typedef __attribute__((ext_vector_type(8))) short short8_t;

// ---------------------------------------------------------------------------
// Kernel A: h = feat @ W^T ; s = h @ a_src ; t = h @ a_dst
// 256 threads, 64 rows/block. Thread tile: 4 rows x 8 cols.
// LDS: Wt (bf16, transposed, 32 KB) + fl (fp32, swizzled, 32 KB) = 64 KB.
// ---------------------------------------------------------------------------
__global__ __launch_bounds__(256) void hst_kernel(
    const float* __restrict__ feat, const float* __restrict__ W,
    const float* __restrict__ a, float* __restrict__ h,
    float* __restrict__ s_out, float* __restrict__ t_out)
{
    __shared__ unsigned short Wt[128 * 128];   // Wt[k*128+d] = bf16(W[d*128+k])
    __shared__ float fl[64 * 128];             // swizzled: fl[r*128 + ((k + 8*(r>>2)) & 127)]
    const int tid = threadIdx.x;
    const long row0 = (long)blockIdx.x * 64;

    for (int i = tid; i < 128 * 128; i += 256) {
        int d = i >> 7, k = i & 127;
        union { float f; unsigned u; } cv; cv.f = W[i];
        // round-to-nearest-even bf16 truncation is fine at 2% tolerance; use RN via intrinsic
        Wt[k * 128 + d] = (unsigned short)(__bfloat16_as_ushort(__float2bfloat16(cv.f)));
    }
    for (int i = tid; i < 64 * 128; i += 256) {
        int r = i >> 7, k = i & 127;
        fl[r * 128 + ((k + 8 * (r >> 2)) & 127)] = feat[(row0 + r) * 128 + k];
    }
    __syncthreads();

    const int oct = tid & 15;   // which 8-col group
    const int rg  = tid >> 4;   // which 4-row group (0..15)
    const int d0  = oct * 8;
    const int r0  = rg * 4;

    float acc[4][8];
    #pragma unroll
    for (int q = 0; q < 4; ++q)
        #pragma unroll
        for (int c = 0; c < 8; ++c) acc[q][c] = 0.f;

    for (int kc = 0; kc < 128; kc += 4) {
        float wv[4][8];
        #pragma unroll
        for (int kk = 0; kk < 4; ++kk) {
            short8_t wr = *reinterpret_cast<const short8_t*>(&Wt[(kc + kk) * 128 + d0]);
            #pragma unroll
            for (int c = 0; c < 8; ++c) {
                union { unsigned u; float f; } cv;
                cv.u = ((unsigned)(unsigned short)wr[c]) << 16;
                wv[kk][c] = cv.f;
            }
        }
        #pragma unroll
        for (int q = 0; q < 4; ++q) {
            int r = r0 + q;
            int koff = (kc + 8 * (r >> 2)) & 127;   // multiple of 4, <=124 -> contiguous, aligned
            float4 fv = *reinterpret_cast<const float4*>(&fl[r * 128 + koff]);
            float fq[4] = {fv.x, fv.y, fv.z, fv.w};
            #pragma unroll
            for (int kk = 0; kk < 4; ++kk)
                #pragma unroll
                for (int c = 0; c < 8; ++c)
                    acc[q][c] = fmaf(fq[kk], wv[kk][c], acc[q][c]);
        }
    }

    float asrc[8], adst[8];
    #pragma unroll
    for (int c = 0; c < 8; ++c) { asrc[c] = a[d0 + c]; adst[c] = a[128 + d0 + c]; }

    #pragma unroll
    for (int q = 0; q < 4; ++q) {
        long row = row0 + r0 + q;
        float4 h0 = make_float4(acc[q][0], acc[q][1], acc[q][2], acc[q][3]);
        float4 h1 = make_float4(acc[q][4], acc[q][5], acc[q][6], acc[q][7]);
        *reinterpret_cast<float4*>(&h[row * 128 + d0])     = h0;
        *reinterpret_cast<float4*>(&h[row * 128 + d0 + 4]) = h1;
        float sv = 0.f, tv = 0.f;
        #pragma unroll
        for (int c = 0; c < 8; ++c) {
            sv = fmaf(acc[q][c], asrc[c], sv);
            tv = fmaf(acc[q][c], adst[c], tv);
        }
        // reduce over the 16 octs; they all live in the same wave (lane bits 0..3)
        #pragma unroll
        for (int off = 1; off < 16; off <<= 1) {
            sv += __shfl_xor(sv, off);
            tv += __shfl_xor(tv, off);
        }
        if (oct == 0) { s_out[row] = sv; t_out[row] = tv; }
    }
}

// ---------------------------------------------------------------------------
// Kernel B: per (b,i) row -> masked-softmax over neighbors -> out = attn @ h
// 128 threads/block, one block per row. Sparse compaction in LDS.
// ---------------------------------------------------------------------------
__global__ __launch_bounds__(128) void attn_kernel(
    const float* __restrict__ adj, const float* __restrict__ h,
    const float* __restrict__ s_in, const float* __restrict__ t_in,
    float* __restrict__ out)
{
    __shared__ int   lj[N_];
    __shared__ float lp[N_];
    __shared__ int   cnt;
    __shared__ float redm[2], reds[2];

    const int tid = threadIdx.x;
    const int row = blockIdx.x;        // b*N + i
    const int b   = row >> 10;
    const float s_i = s_in[row];
    const float* __restrict__ arow = adj + (size_t)row * N_;
    const float* __restrict__ trow = t_in + (size_t)b * N_;

    if (tid == 0) cnt = 0;
    __syncthreads();

    float m = -3.0e38f;
    #pragma unroll
    for (int half = 0; half < 2; ++half) {
        int j0 = half * 512 + tid * 4;
        float4 av = *reinterpret_cast<const float4*>(arow + j0);
        #pragma unroll
        for (int q = 0; q < 4; ++q) {
            float aq = (&av.x)[q];
            if (aq == 1.0f) {
                float sc = s_i + trow[j0 + q];
                sc = sc > 0.f ? sc : ALPHA_ * sc;
                m = fmaxf(m, sc);
                int idx = atomicAdd(&cnt, 1);
                lj[idx] = j0 + q;
                lp[idx] = sc;
            }
        }
    }
    #pragma unroll
    for (int off = 32; off; off >>= 1) m = fmaxf(m, __shfl_xor(m, off));
    if ((tid & 63) == 0) redm[tid >> 6] = m;
    __syncthreads();                       // list + cnt + redm now visible
    m = fmaxf(redm[0], redm[1]);
    const int c = cnt;

    float sum = 0.f;
    for (int k = tid; k < c; k += 128) {
        float p = __expf(lp[k] - m);
        lp[k] = p;
        sum += p;
    }
    #pragma unroll
    for (int off = 32; off; off >>= 1) sum += __shfl_xor(sum, off);
    __syncthreads();                       // all lp[] rewrites done
    if ((tid & 63) == 0) reds[tid >> 6] = sum;
    __syncthreads();
    const float inv = 1.0f / (reds[0] + reds[1]);

    // out[row, tid] = (1/sum) * sum_k p_k * h[b, j_k, tid]
    const float* __restrict__ hb = h + (size_t)b * N_ * F_;
    float acc = 0.f;
    for (int k = 0; k < c; ++k) {
        acc = fmaf(lp[k], hb[(size_t)lj[k] * F_ + tid], acc);
    }
    out[(size_t)row * F_ + tid] = acc * inv;
}

// ---------------------------------------------------------------------------
extern "C" void kernel_launch(void* const* d_in, const int* in_sizes, int n_in,
                              void* d_out, int out_size, void* d_ws, size_t ws_size,
                              hipStream_t stream)
{
    const float* adj  = (const float*)d_in[0];   // (32,1024,1024)
    const float* feat = (const float*)d_in[1];   // (32,1024,128)
    const float* W    = (const float*)d_in[2];   // (128,128)
    const float* a    = (const float*)d_in[3];   // (256,1)
    float* out = (float*)d_out;                  // (32,1024,128) fp32

    float* h = (float*)d_ws;                     // 32*1024*128 floats = 16 MB
    float* s = h + (size_t)B_ * N_ * F_;         // 32*1024
    float* t = s + (size_t)B_ * N_;              // 32*1024

    hst_kernel<<<(B_ * N_) / 64, 256, 0, stream>>>(feat, W, a, h, s, t);
    attn_kernel<<<B_ * N_, 128, 0, stream>>>(adj, h, s, t, out);
}

// Round 2
// 85.877 us; speedup vs baseline: 1.1955x; 1.1955x over previous
//
#include <hip/hip_runtime.h>
#include <hip/hip_bf16.h>

#define B_ 32
#define N_ 1024
#define F_ 128
#define ALPHA_ 0.2f

typedef __attribute__((ext_vector_type(8))) short short8_t;

// ---------------------------------------------------------------------------
// Kernel A: h = feat @ W^T ; s = h @ a_src ; t = h @ a_dst
// 256 threads, 64 rows/block. Thread tile: 4 rows x 8 cols.
// LDS: Wt (bf16, transposed, 32 KB) + fl (fp32, swizzled, 32 KB) = 64 KB.
// ---------------------------------------------------------------------------
__global__ __launch_bounds__(256) void hst_kernel(
    const float* __restrict__ feat, const float* __restrict__ W,
    const float* __restrict__ a, float* __restrict__ h,
    float* __restrict__ s_out, float* __restrict__ t_out)
{
    __shared__ unsigned short Wt[128 * 128];   // Wt[k*128+d] = bf16(W[d*128+k])
    __shared__ float fl[64 * 128];             // swizzled: fl[r*128 + ((k + 8*(r>>2)) & 127)]
    const int tid = threadIdx.x;
    const long row0 = (long)blockIdx.x * 64;

    for (int i = tid; i < 128 * 128; i += 256) {
        int d = i >> 7, k = i & 127;
        Wt[k * 128 + d] = (unsigned short)(__bfloat16_as_ushort(__float2bfloat16(W[i])));
    }
    for (int i = tid; i < 64 * 128; i += 256) {
        int r = i >> 7, k = i & 127;
        fl[r * 128 + ((k + 8 * (r >> 2)) & 127)] = feat[(row0 + r) * 128 + k];
    }
    __syncthreads();

    const int oct = tid & 15;   // which 8-col group
    const int rg  = tid >> 4;   // which 4-row group (0..15)
    const int d0  = oct * 8;
    const int r0  = rg * 4;

    float acc[4][8];
    #pragma unroll
    for (int q = 0; q < 4; ++q)
        #pragma unroll
        for (int c = 0; c < 8; ++c) acc[q][c] = 0.f;

    for (int kc = 0; kc < 128; kc += 4) {
        float wv[4][8];
        #pragma unroll
        for (int kk = 0; kk < 4; ++kk) {
            short8_t wr = *reinterpret_cast<const short8_t*>(&Wt[(kc + kk) * 128 + d0]);
            #pragma unroll
            for (int c = 0; c < 8; ++c) {
                union { unsigned u; float f; } cv;
                cv.u = ((unsigned)(unsigned short)wr[c]) << 16;
                wv[kk][c] = cv.f;
            }
        }
        #pragma unroll
        for (int q = 0; q < 4; ++q) {
            int r = r0 + q;
            int koff = (kc + 8 * (r >> 2)) & 127;
            float4 fv = *reinterpret_cast<const float4*>(&fl[r * 128 + koff]);
            float fq[4] = {fv.x, fv.y, fv.z, fv.w};
            #pragma unroll
            for (int kk = 0; kk < 4; ++kk)
                #pragma unroll
                for (int c = 0; c < 8; ++c)
                    acc[q][c] = fmaf(fq[kk], wv[kk][c], acc[q][c]);
        }
    }

    float asrc[8], adst[8];
    #pragma unroll
    for (int c = 0; c < 8; ++c) { asrc[c] = a[d0 + c]; adst[c] = a[128 + d0 + c]; }

    #pragma unroll
    for (int q = 0; q < 4; ++q) {
        long row = row0 + r0 + q;
        float4 h0 = make_float4(acc[q][0], acc[q][1], acc[q][2], acc[q][3]);
        float4 h1 = make_float4(acc[q][4], acc[q][5], acc[q][6], acc[q][7]);
        *reinterpret_cast<float4*>(&h[row * 128 + d0])     = h0;
        *reinterpret_cast<float4*>(&h[row * 128 + d0 + 4]) = h1;
        float sv = 0.f, tv = 0.f;
        #pragma unroll
        for (int c = 0; c < 8; ++c) {
            sv = fmaf(acc[q][c], asrc[c], sv);
            tv = fmaf(acc[q][c], adst[c], tv);
        }
        #pragma unroll
        for (int off = 1; off < 16; off <<= 1) {
            sv += __shfl_xor(sv, off);
            tv += __shfl_xor(tv, off);
        }
        if (oct == 0) { s_out[row] = sv; t_out[row] = tv; }
    }
}

// ---------------------------------------------------------------------------
// Kernel B v2: per (b,i) row. Packed (j,p) float2 list; exp-pass pads list to
// a multiple of 8; gather loop runs 8 independent loads per batch (MLP fix).
// ---------------------------------------------------------------------------
__global__ __launch_bounds__(128) void attn_kernel(
    const float* __restrict__ adj, const float* __restrict__ h,
    const float* __restrict__ s_in, const float* __restrict__ t_in,
    float* __restrict__ out)
{
    __shared__ float2 ljp[N_];          // .x = j (int bits), .y = score -> p
    __shared__ int   cnt;
    __shared__ float redm[2], reds[2];

    const int tid = threadIdx.x;
    const int row = blockIdx.x;        // b*N + i
    const int b   = row >> 10;
    const float s_i = s_in[row];
    const float4* __restrict__ arow4 = (const float4*)(adj + (size_t)row * N_);
    const float4* __restrict__ trow4 = (const float4*)(t_in + (size_t)b * N_);

    if (tid == 0) cnt = 0;
    __syncthreads();

    // Issue all 4 row loads up front (independent, coalesced).
    float4 av0 = arow4[tid];
    float4 av1 = arow4[tid + 128];
    float4 tv0 = trow4[tid];
    float4 tv1 = trow4[tid + 128];

    float mt = -3.0e38f;
    #pragma unroll
    for (int q = 0; q < 4; ++q) {
        if ((&av0.x)[q] == 1.0f) {
            float sc = s_i + (&tv0.x)[q];
            sc = sc > 0.f ? sc : ALPHA_ * sc;
            mt = fmaxf(mt, sc);
            int idx = atomicAdd(&cnt, 1);
            ljp[idx] = make_float2(__int_as_float(tid * 4 + q), sc);
        }
    }
    #pragma unroll
    for (int q = 0; q < 4; ++q) {
        if ((&av1.x)[q] == 1.0f) {
            float sc = s_i + (&tv1.x)[q];
            sc = sc > 0.f ? sc : ALPHA_ * sc;
            mt = fmaxf(mt, sc);
            int idx = atomicAdd(&cnt, 1);
            ljp[idx] = make_float2(__int_as_float(512 + tid * 4 + q), sc);
        }
    }
    #pragma unroll
    for (int off = 32; off; off >>= 1) mt = fmaxf(mt, __shfl_xor(mt, off));
    if ((tid & 63) == 0) redm[tid >> 6] = mt;
    __syncthreads();                       // #1: cnt, ljp, redm visible

    const int   c  = cnt;
    const int   cp = (c + 7) & ~7;         // padded count (>=8, diag guarantees c>=1)
    const float m  = fmaxf(redm[0], redm[1]);
    const float j0x = ljp[0].x;            // safe index for pad entries

    float sum = 0.f;
    for (int k = tid; k < cp; k += 128) {
        float p, jx;
        if (k < c) { float2 e = ljp[k]; p = __expf(e.y - m); jx = e.x; }
        else       { p = 0.f; jx = j0x; }
        ljp[k] = make_float2(jx, p);
        sum += p;
    }
    #pragma unroll
    for (int off = 32; off; off >>= 1) sum += __shfl_xor(sum, off);
    if ((tid & 63) == 0) reds[tid >> 6] = sum;
    __syncthreads();                       // #2: exp rewrites + reds visible

    const float inv = 1.0f / (reds[0] + reds[1]);

    // out[row, tid] = inv * sum_k p_k * h[b, j_k, tid], 8 loads in flight
    const float* __restrict__ hb = h + (size_t)b * (N_ * F_);
    float acc = 0.f;
    for (int k = 0; k < cp; k += 8) {
        float2 e[8];
        #pragma unroll
        for (int q = 0; q < 8; ++q) e[q] = ljp[k + q];   // broadcast ds_read_b64
        float v[8];
        #pragma unroll
        for (int q = 0; q < 8; ++q)
            v[q] = hb[(size_t)__float_as_int(e[q].x) * F_ + tid];
        #pragma unroll
        for (int q = 0; q < 8; ++q) acc = fmaf(e[q].y, v[q], acc);
    }
    out[(size_t)row * F_ + tid] = acc * inv;
}

// ---------------------------------------------------------------------------
extern "C" void kernel_launch(void* const* d_in, const int* in_sizes, int n_in,
                              void* d_out, int out_size, void* d_ws, size_t ws_size,
                              hipStream_t stream)
{
    const float* adj  = (const float*)d_in[0];   // (32,1024,1024)
    const float* feat = (const float*)d_in[1];   // (32,1024,128)
    const float* W    = (const float*)d_in[2];   // (128,128)
    const float* a    = (const float*)d_in[3];   // (256,1)
    float* out = (float*)d_out;                  // (32,1024,128) fp32

    float* h = (float*)d_ws;                     // 16 MB
    float* s = h + (size_t)B_ * N_ * F_;
    float* t = s + (size_t)B_ * N_;

    hst_kernel<<<(B_ * N_) / 64, 256, 0, stream>>>(feat, W, a, h, s, t);
    attn_kernel<<<B_ * N_, 128, 0, stream>>>(adj, h, s, t, out);
}